// Round 5
// baseline (396.586 us; speedup 1.0000x reference)
//
#include <hip/hip_runtime.h>
#include <hip/hip_fp16.h>

#define N_POINTS 500000
#define BN_EPS 1e-5f
#define A_COEF -0.75f

typedef __attribute__((ext_vector_type(8))) short short8;
typedef __attribute__((ext_vector_type(4))) float floatx4;
typedef unsigned short ushort_t;
typedef unsigned int uint_t;

// -------- workspace layout (float offsets) --------
#define WS_WBF_OFF    0                          // bf16 weights [tap(9)][oc(64)][ic(64)]   : 18432 floats
#define WS_CONV_OFF   18432                      // conv HWC fp32 [3][128][128][64]          : 3145728
#define WS_SUM_OFF    (WS_CONV_OFF + 3145728)    // [3][64]                                  : 192
#define WS_SUMSQ_OFF  (WS_SUM_OFF + 192)
#define WS_SCALE_OFF  (WS_SUMSQ_OFF + 192)
#define WS_SHIFT_OFF  (WS_SCALE_OFF + 192)
#define WS_PLANES_OFF (WS_SHIFT_OFF + 192)       // fp16 planes, SPLIT layout [h(2)][pl(3)][pix(16384)][32ch] : 1572864 floats
#define WS_INBF_OFF   (WS_PLANES_OFF + 1572864)  // bf16 input HWC [3][256][256][64]         : 6291456 floats
// total ~44.1 MB

__device__ __forceinline__ ushort_t f2bf(float f) {
  uint_t u = __float_as_uint(f);
  uint_t r = (u + 0x7fffu + ((u >> 16) & 1u)) >> 16;
  return (ushort_t)r;
}
__device__ __forceinline__ float bf2f(ushort_t u) {
  return __uint_as_float(((uint_t)u) << 16);
}

// ================= prep: weights [oc][ic][3][3] fp32 -> [tap][oc][ic] bf16; zero stat accums
__global__ __launch_bounds__(256) void wprep_kernel(const float* __restrict__ w_in,
                                                    float* __restrict__ ws) {
  int i = blockIdx.x * 256 + threadIdx.x;  // < 36864
  if (i < 36864) {
    int ic = i & 63;
    int oc = (i >> 6) & 63;
    int kk = i >> 12;  // 0..8
    ((ushort_t*)(ws + WS_WBF_OFF))[i] = f2bf(w_in[(oc * 64 + ic) * 9 + kk]);
  }
  if (i < 384) ws[WS_SUM_OFF + i] = 0.0f;  // sums + sumsq contiguous
}

// ================= transpose: input CHW fp32 -> HWC bf16
// grid (4, 256, 3): x-tile, row y, plane
__global__ __launch_bounds__(256) void transpose_kernel(const float* __restrict__ p0,
                                                        const float* __restrict__ p1,
                                                        const float* __restrict__ p2,
                                                        float* __restrict__ ws) {
  __shared__ float tile[64][65];
  const int xt = blockIdx.x, y = blockIdx.y, pl = blockIdx.z;
  const float* src = (pl == 0) ? p0 : ((pl == 1) ? p1 : p2);
  ushort_t* dst = (ushort_t*)(ws + WS_INBF_OFF) + pl * (256 * 256 * 64);
  const int t = threadIdx.x;
  const int x0 = xt * 64;
  for (int i = t; i < 4096; i += 256) {
    int c = i >> 6, x = i & 63;
    tile[x][c] = src[(c * 256 + y) * 256 + x0 + x];
  }
  __syncthreads();
  uint_t* du = (uint_t*)dst;
  for (int i = t; i < 2048; i += 256) {
    int x = i >> 5, cp = (i & 31) * 2;
    uint_t lo = f2bf(tile[x][cp]);
    uint_t hi = f2bf(tile[x][cp + 1]);
    du[((y * 256 + x0 + x) * 64 + cp) >> 1] = (hi << 16) | lo;
  }
}

// ================= conv3x3 stride2 pad1 via MFMA bf16 (bias dropped: cancels in batch-stat BN)
// grid (2, 128, 3). 4 waves; wave computes 16 px x 64 oc. A from global HWC bf16, B from bf16 weights.
__global__ __launch_bounds__(256) void conv_mfma_kernel(const float* __restrict__ ws_r,
                                                        float* __restrict__ ws) {
  const int xh = blockIdx.x, oy = blockIdx.y, pz = blockIdx.z;
  const int t = threadIdx.x;
  const int wv = t >> 6, lane = t & 63;
  const int mn = lane & 15;   // A: px row m ; B: oc col n
  const int kg = lane >> 4;   // k-group (k = kg*8 + j)
  const int x0w = xh * 64 + wv * 16;

  const ushort_t* inb = (const ushort_t*)(ws_r + WS_INBF_OFF) + pz * (256 * 256 * 64);
  const ushort_t* wbf = (const ushort_t*)(ws_r + WS_WBF_OFF);

  floatx4 acc[4] = {{0.f,0.f,0.f,0.f},{0.f,0.f,0.f,0.f},{0.f,0.f,0.f,0.f},{0.f,0.f,0.f,0.f}};

  for (int ky = 0; ky < 3; ky++) {
    int y = 2 * oy - 1 + ky;
    if (y < 0) continue;  // y <= 255 always
    const ushort_t* rowp = inb + y * (256 * 64);
    for (int kx = 0; kx < 3; kx++) {
      int xm = 2 * (x0w + mn) - 1 + kx;     // only -1 can be OOB (max 255)
      bool vx = xm >= 0;
      int xc = vx ? xm : 0;
      const ushort_t* abase = rowp + xc * 64 + kg * 8;
      const ushort_t* wbase = wbf + ((ky * 3 + kx) * 64 + mn) * 64 + kg * 8;
#pragma unroll
      for (int kc = 0; kc < 2; kc++) {
        union { int4 i4; short8 s8; } au;
        au.i4 = *reinterpret_cast<const int4*>(abase + kc * 32);
        if (!vx) au.i4 = make_int4(0, 0, 0, 0);
#pragma unroll
        for (int nt = 0; nt < 4; nt++) {
          union { int4 i4; short8 s8; } bu;
          bu.i4 = *reinterpret_cast<const int4*>(wbase + nt * 1024 + kc * 32);
          acc[nt] = __builtin_amdgcn_mfma_f32_16x16x32_bf16(au.s8, bu.s8, acc[nt], 0, 0, 0);
        }
      }
    }
  }
  // D: col(oc) = lane&15, row(px) = (lane>>4)*4 + reg
  float* cout = ws + WS_CONV_OFF + ((pz * 128 + oy) * 128 + x0w) * 64;
#pragma unroll
  for (int nt = 0; nt < 4; nt++) {
#pragma unroll
    for (int r = 0; r < 4; r++) {
      cout[(kg * 4 + r) * 64 + nt * 16 + mn] = acc[nt][r];
    }
  }
}

// ================= BN stats: per (plane, channel) sum & sumsq over 16384 px
__global__ __launch_bounds__(256) void stats_kernel(float* __restrict__ ws) {
  const int b = blockIdx.x;
  const int plane = b >> 6, chunk = b & 63;
  const int t = threadIdx.x;
  const int c = t & 63, g = t >> 6;
  const float* base = ws + WS_CONV_OFF + plane * (16384 * 64);
  float s = 0.0f, s2 = 0.0f;
  const int row0 = chunk * 256 + g * 64;
  for (int i = 0; i < 64; i++) {
    float v = base[(row0 + i) * 64 + c];
    s += v;
    s2 = fmaf(v, v, s2);
  }
  __shared__ float rs[256], rs2[256];
  rs[t] = s; rs2[t] = s2;
  __syncthreads();
  if (t < 64) {
    s = rs[t] + rs[t + 64] + rs[t + 128] + rs[t + 192];
    s2 = rs2[t] + rs2[t + 64] + rs2[t + 128] + rs2[t + 192];
    atomicAdd(&ws[WS_SUM_OFF + plane * 64 + c], s);
    atomicAdd(&ws[WS_SUMSQ_OFF + plane * 64 + c], s2);
  }
}

__global__ void finalize_kernel(const float* __restrict__ gamma,
                                const float* __restrict__ beta,
                                float* __restrict__ ws) {
  int i = threadIdx.x;
  if (i < 192) {
    int c = i & 63;
    float mu = ws[WS_SUM_OFF + i] * (1.0f / 16384.0f);
    float var = ws[WS_SUMSQ_OFF + i] * (1.0f / 16384.0f) - mu * mu;
    var = fmaxf(var, 0.0f);
    float rstd = 1.0f / sqrtf(var + BN_EPS);
    float sc = gamma[c] * rstd;
    ws[WS_SCALE_OFF + i] = sc;
    ws[WS_SHIFT_OFF + i] = beta[c] - mu * sc;
  }
}

// ================= apply BN + relu + fused avgpool(3x3 s2 p1, count_include_pad) + pack fp16
// thread = (plane, px, 8-channel group); 393216 threads
// Writes the SPLIT plane layout: [h=cb/32][pl][pix][32ch]
__global__ __launch_bounds__(256) void apply_kernel(float* __restrict__ ws,
                                                    __half* __restrict__ planes) {
  int idx = blockIdx.x * 256 + threadIdx.x;  // < 393216
  int g = idx & 7;
  int p = (idx >> 3) & 16383;
  int pl = idx >> 17;
  int oy = p >> 7, ox = p & 127;
  int cb = g * 8;

  const float* conv = ws + WS_CONV_OFF;
  float4 a0 = *reinterpret_cast<const float4*>(conv + (size_t)idx * 8);
  float4 a1 = *reinterpret_cast<const float4*>(conv + (size_t)idx * 8 + 4);

  float sc[8], sh[8];
#pragma unroll
  for (int k = 0; k < 8; k++) {
    sc[k] = ws[WS_SCALE_OFF + pl * 64 + cb + k];
    sh[k] = ws[WS_SHIFT_OFF + pl * 64 + cb + k];
  }

  const ushort_t* inb = (const ushort_t*)(ws + WS_INBF_OFF) + pl * (256 * 256 * 64);
  float ps[8];
#pragma unroll
  for (int k = 0; k < 8; k++) ps[k] = 0.0f;
#pragma unroll
  for (int r = 0; r < 3; r++) {
    int yy = 2 * oy - 1 + r;
    if (yy < 0) continue;  // <= 255 always
#pragma unroll
    for (int s = 0; s < 3; s++) {
      int xx = 2 * ox - 1 + s;
      if (xx < 0) continue;
      union { int4 i4; ushort_t u[8]; } ub;
      ub.i4 = *reinterpret_cast<const int4*>(inb + (yy * 256 + xx) * 64 + cb);
#pragma unroll
      for (int k = 0; k < 8; k++) ps[k] += bf2f(ub.u[k]);
    }
  }

  float v[8] = {a0.x, a0.y, a0.z, a0.w, a1.x, a1.y, a1.z, a1.w};
  union { int4 i4; __half h[8]; } ob;
#pragma unroll
  for (int k = 0; k < 8; k++) {
    float r = fmaxf(fmaf(v[k], sc[k], sh[k]), 0.0f) + ps[k] * (1.0f / 9.0f);
    ob.h[k] = __float2half(r);
  }
  // split layout: h = g>>2 (channel half), sub-group g&3
  int h = g >> 2;
  size_t didx = (((size_t)(h * 3 + pl) * 16384 + p) * 4 + (g & 3));
  *reinterpret_cast<int4*>(planes + didx * 8) = ob.i4;
}

// ================= bicubic sampling, 3 planes fused
__device__ __forceinline__ void cubic_w(float t, float w[4]) {
  float t1 = t + 1.0f;
  w[0] = ((A_COEF * t1 - 5.0f * A_COEF) * t1 + 8.0f * A_COEF) * t1 - 4.0f * A_COEF;
  w[1] = ((A_COEF + 2.0f) * t - (A_COEF + 3.0f)) * t * t + 1.0f;
  float s = 1.0f - t;
  w[2] = ((A_COEF + 2.0f) * s - (A_COEF + 3.0f)) * s * s + 1.0f;
  w[3] = 1.0f - w[0] - w[1] - w[2];
}

// One tap = one asm block: 8x v_fma_mix_f32 (fpext(f16)*w + acc, exact fma-f32
// numerics). Single block keeps the 8 accumulators pinned across all 48 taps.
__device__ __forceinline__ void fma_mix_tap(float& a0, float& a1, float& a2, float& a3,
                                            float& a4, float& a5, float& a6, float& a7,
                                            uint4 q, float w) {
  asm("v_fma_mix_f32 %0, %8, %12, %0 op_sel:[0,0,0] op_sel_hi:[1,0,0]\n\t"
      "v_fma_mix_f32 %1, %8, %12, %1 op_sel:[1,0,0] op_sel_hi:[1,0,0]\n\t"
      "v_fma_mix_f32 %2, %9, %12, %2 op_sel:[0,0,0] op_sel_hi:[1,0,0]\n\t"
      "v_fma_mix_f32 %3, %9, %12, %3 op_sel:[1,0,0] op_sel_hi:[1,0,0]\n\t"
      "v_fma_mix_f32 %4, %10, %12, %4 op_sel:[0,0,0] op_sel_hi:[1,0,0]\n\t"
      "v_fma_mix_f32 %5, %10, %12, %5 op_sel:[1,0,0] op_sel_hi:[1,0,0]\n\t"
      "v_fma_mix_f32 %6, %11, %12, %6 op_sel:[0,0,0] op_sel_hi:[1,0,0]\n\t"
      "v_fma_mix_f32 %7, %11, %12, %7 op_sel:[1,0,0] op_sel_hi:[1,0,0]"
      : "+v"(a0), "+v"(a1), "+v"(a2), "+v"(a3),
        "+v"(a4), "+v"(a5), "+v"(a6), "+v"(a7)
      : "v"(q.x), "v"(q.y), "v"(q.z), "v"(q.w), "v"(w));
}

// v5: channel-split sampling. One dispatch per channel-half h; per-dispatch
// plane footprint = 3*128*128*32*2B = 3.15 MB < 4 MiB/XCD L2 -> L2-resident.
// Group of 4 lanes = one point (32 ch); lane handles channels h*32+l*8..+8.
// nt stores keep the 62.5 MB/dispatch write stream from evicting the planes.
__global__ __launch_bounds__(256) void sample_kernel(const float* __restrict__ coords,
                                                     const float* __restrict__ noise,
                                                     const __half* __restrict__ planes,
                                                     float* __restrict__ out,
                                                     const int h) {
  const int t = threadIdx.x;
  const int wv = t >> 6, lane = t & 63;
  const int g = lane >> 2, l = lane & 3;
  const int n = blockIdx.x * 64 + wv * 16 + g;
  if (n >= N_POINTS) return;

  const float c0 = (coords[n * 3 + 0] + 1.0f) * 0.5f;
  const float c1 = (coords[n * 3 + 1] + 1.0f) * 0.5f;
  const float c2 = (coords[n * 3 + 2] + 1.0f) * 0.5f;

  float a0 = 0.f, a1 = 0.f, a2 = 0.f, a3 = 0.f;
  float a4 = 0.f, a5 = 0.f, a6 = 0.f, a7 = 0.f;

#pragma unroll
  for (int p = 0; p < 3; p++) {
    float u = (p == 1) ? c1 : c0;   // p0:(c0,c1) p1:(c1,c2) p2:(c0,c2)
    float v = (p == 0) ? c1 : c2;
    u += noise[(p * N_POINTS + n) * 2 + 0];
    v += noise[(p * N_POINTS + n) * 2 + 1];
    float gx = fminf(fmaxf(fmaf(u, 63.5f, 63.5f), 0.0f), 127.0f);
    float gy = fminf(fmaxf(fmaf(v, 63.5f, 63.5f), 0.0f), 127.0f);
    float x0f = floorf(gx), y0f = floorf(gy);
    float tx = gx - x0f, ty = gy - y0f;
    int ix = (int)x0f, iy = (int)y0f;
    float wx[4], wy[4];
    cubic_w(tx, wx);
    cubic_w(ty, wy);

    // 32-bit element offsets: [(h*3+p)*16384 + pix]*32 + l*8
    const int rb = (h * 3 + p) * (16384 * 32) + l * 8;
    int ro[4], xo[4];
#pragma unroll
    for (int i = 0; i < 4; i++) ro[i] = rb + min(max(iy - 1 + i, 0), 127) * (128 * 32);
#pragma unroll
    for (int j = 0; j < 4; j++) xo[j] = min(max(ix - 1 + j, 0), 127) * 32;

    uint4 q[16];
#pragma unroll
    for (int i = 0; i < 4; i++) {
#pragma unroll
      for (int j = 0; j < 4; j++) {
        q[i * 4 + j] = *reinterpret_cast<const uint4*>(planes + ro[i] + xo[j]);
      }
    }

#pragma unroll
    for (int i = 0; i < 4; i++) {
#pragma unroll
      for (int j = 0; j < 4; j++) {
        float w = wy[i] * wx[j];
        fma_mix_tap(a0, a1, a2, a3, a4, a5, a6, a7, q[i * 4 + j], w);
      }
    }
  }

  float* op = out + (size_t)n * 64 + h * 32 + l * 8;
  floatx4 o0 = {a0, a1, a2, a3};
  floatx4 o1 = {a4, a5, a6, a7};
  __builtin_nontemporal_store(o0, reinterpret_cast<floatx4*>(op));
  __builtin_nontemporal_store(o1, reinterpret_cast<floatx4*>(op + 4));
}

extern "C" void kernel_launch(void* const* d_in, const int* in_sizes, int n_in,
                              void* d_out, int out_size, void* d_ws, size_t ws_size,
                              hipStream_t stream) {
  const float* coords = (const float*)d_in[0];
  const float* noise  = (const float*)d_in[1];
  const float* px     = (const float*)d_in[2];
  const float* py     = (const float*)d_in[3];
  const float* pz     = (const float*)d_in[4];
  const float* conv_w = (const float*)d_in[5];
  // conv_b (d_in[6]) unused: bias cancels exactly under batch-stat BN
  const float* gamma  = (const float*)d_in[7];
  const float* beta   = (const float*)d_in[8];
  float* out = (float*)d_out;
  float* ws = (float*)d_ws;
  __half* planes = (__half*)(ws + WS_PLANES_OFF);

  wprep_kernel<<<144, 256, 0, stream>>>(conv_w, ws);
  transpose_kernel<<<dim3(4, 256, 3), 256, 0, stream>>>(px, py, pz, ws);
  conv_mfma_kernel<<<dim3(2, 128, 3), 256, 0, stream>>>(ws, ws);
  stats_kernel<<<192, 256, 0, stream>>>(ws);
  finalize_kernel<<<1, 256, 0, stream>>>(gamma, beta, ws);
  apply_kernel<<<1536, 256, 0, stream>>>(ws, planes);
  const int nblk = (N_POINTS + 63) / 64;  // 7813
  sample_kernel<<<nblk, 256, 0, stream>>>(coords, noise, planes, out, 0);
  sample_kernel<<<nblk, 256, 0, stream>>>(coords, noise, planes, out, 1);
}

// Round 6
// 350.227 us; speedup vs baseline: 1.1324x; 1.1324x over previous
//
#include <hip/hip_runtime.h>
#include <hip/hip_fp16.h>

#define N_POINTS 500000
#define BN_EPS 1e-5f
#define A_COEF -0.75f

typedef __attribute__((ext_vector_type(8))) short short8;
typedef __attribute__((ext_vector_type(4))) float floatx4;
typedef unsigned short ushort_t;
typedef unsigned int uint_t;
typedef __attribute__((ext_vector_type(4))) uint_t uintx4;

// -------- workspace layout (float offsets) --------
#define WS_WBF_OFF    0                          // bf16 weights [tap(9)][oc(64)][ic(64)]   : 18432 floats
#define WS_CONV_OFF   18432                      // conv HWC fp32 [3][128][128][64]          : 3145728
#define WS_SUM_OFF    (WS_CONV_OFF + 3145728)    // [3][64]                                  : 192
#define WS_SUMSQ_OFF  (WS_SUM_OFF + 192)
#define WS_SCALE_OFF  (WS_SUMSQ_OFF + 192)
#define WS_SHIFT_OFF  (WS_SCALE_OFF + 192)
#define WS_PLANES_OFF (WS_SHIFT_OFF + 192)       // fp16 planes HWC [3][128][128][64]        : 1572864 floats
#define WS_INBF_OFF   (WS_PLANES_OFF + 1572864)  // bf16 input HWC [3][256][256][64]         : 6291456 floats
// total ~44.1 MB

__device__ __forceinline__ ushort_t f2bf(float f) {
  uint_t u = __float_as_uint(f);
  uint_t r = (u + 0x7fffu + ((u >> 16) & 1u)) >> 16;
  return (ushort_t)r;
}
__device__ __forceinline__ float bf2f(ushort_t u) {
  return __uint_as_float(((uint_t)u) << 16);
}

// ================= prep: weights [oc][ic][3][3] fp32 -> [tap][oc][ic] bf16; zero stat accums
__global__ __launch_bounds__(256) void wprep_kernel(const float* __restrict__ w_in,
                                                    float* __restrict__ ws) {
  int i = blockIdx.x * 256 + threadIdx.x;  // < 36864
  if (i < 36864) {
    int ic = i & 63;
    int oc = (i >> 6) & 63;
    int kk = i >> 12;  // 0..8
    ((ushort_t*)(ws + WS_WBF_OFF))[i] = f2bf(w_in[(oc * 64 + ic) * 9 + kk]);
  }
  if (i < 384) ws[WS_SUM_OFF + i] = 0.0f;  // sums + sumsq contiguous
}

// ================= transpose: input CHW fp32 -> HWC bf16
// grid (4, 256, 3): x-tile, row y, plane
__global__ __launch_bounds__(256) void transpose_kernel(const float* __restrict__ p0,
                                                        const float* __restrict__ p1,
                                                        const float* __restrict__ p2,
                                                        float* __restrict__ ws) {
  __shared__ float tile[64][65];
  const int xt = blockIdx.x, y = blockIdx.y, pl = blockIdx.z;
  const float* src = (pl == 0) ? p0 : ((pl == 1) ? p1 : p2);
  ushort_t* dst = (ushort_t*)(ws + WS_INBF_OFF) + pl * (256 * 256 * 64);
  const int t = threadIdx.x;
  const int x0 = xt * 64;
  for (int i = t; i < 4096; i += 256) {
    int c = i >> 6, x = i & 63;
    tile[x][c] = src[(c * 256 + y) * 256 + x0 + x];
  }
  __syncthreads();
  uint_t* du = (uint_t*)dst;
  for (int i = t; i < 2048; i += 256) {
    int x = i >> 5, cp = (i & 31) * 2;
    uint_t lo = f2bf(tile[x][cp]);
    uint_t hi = f2bf(tile[x][cp + 1]);
    du[((y * 256 + x0 + x) * 64 + cp) >> 1] = (hi << 16) | lo;
  }
}

// ================= conv3x3 stride2 pad1 via MFMA bf16 (bias dropped: cancels in batch-stat BN)
// grid (2, 128, 3). 4 waves; wave computes 16 px x 64 oc. A from global HWC bf16, B from bf16 weights.
__global__ __launch_bounds__(256) void conv_mfma_kernel(const float* __restrict__ ws_r,
                                                        float* __restrict__ ws) {
  const int xh = blockIdx.x, oy = blockIdx.y, pz = blockIdx.z;
  const int t = threadIdx.x;
  const int wv = t >> 6, lane = t & 63;
  const int mn = lane & 15;   // A: px row m ; B: oc col n
  const int kg = lane >> 4;   // k-group (k = kg*8 + j)
  const int x0w = xh * 64 + wv * 16;

  const ushort_t* inb = (const ushort_t*)(ws_r + WS_INBF_OFF) + pz * (256 * 256 * 64);
  const ushort_t* wbf = (const ushort_t*)(ws_r + WS_WBF_OFF);

  floatx4 acc[4] = {{0.f,0.f,0.f,0.f},{0.f,0.f,0.f,0.f},{0.f,0.f,0.f,0.f},{0.f,0.f,0.f,0.f}};

  for (int ky = 0; ky < 3; ky++) {
    int y = 2 * oy - 1 + ky;
    if (y < 0) continue;  // y <= 255 always
    const ushort_t* rowp = inb + y * (256 * 64);
    for (int kx = 0; kx < 3; kx++) {
      int xm = 2 * (x0w + mn) - 1 + kx;     // only -1 can be OOB (max 255)
      bool vx = xm >= 0;
      int xc = vx ? xm : 0;
      const ushort_t* abase = rowp + xc * 64 + kg * 8;
      const ushort_t* wbase = wbf + ((ky * 3 + kx) * 64 + mn) * 64 + kg * 8;
#pragma unroll
      for (int kc = 0; kc < 2; kc++) {
        union { int4 i4; short8 s8; } au;
        au.i4 = *reinterpret_cast<const int4*>(abase + kc * 32);
        if (!vx) au.i4 = make_int4(0, 0, 0, 0);
#pragma unroll
        for (int nt = 0; nt < 4; nt++) {
          union { int4 i4; short8 s8; } bu;
          bu.i4 = *reinterpret_cast<const int4*>(wbase + nt * 1024 + kc * 32);
          acc[nt] = __builtin_amdgcn_mfma_f32_16x16x32_bf16(au.s8, bu.s8, acc[nt], 0, 0, 0);
        }
      }
    }
  }
  // D: col(oc) = lane&15, row(px) = (lane>>4)*4 + reg
  float* cout = ws + WS_CONV_OFF + ((pz * 128 + oy) * 128 + x0w) * 64;
#pragma unroll
  for (int nt = 0; nt < 4; nt++) {
#pragma unroll
    for (int r = 0; r < 4; r++) {
      cout[(kg * 4 + r) * 64 + nt * 16 + mn] = acc[nt][r];
    }
  }
}

// ================= BN stats: per (plane, channel) sum & sumsq over 16384 px
__global__ __launch_bounds__(256) void stats_kernel(float* __restrict__ ws) {
  const int b = blockIdx.x;
  const int plane = b >> 6, chunk = b & 63;
  const int t = threadIdx.x;
  const int c = t & 63, g = t >> 6;
  const float* base = ws + WS_CONV_OFF + plane * (16384 * 64);
  float s = 0.0f, s2 = 0.0f;
  const int row0 = chunk * 256 + g * 64;
  for (int i = 0; i < 64; i++) {
    float v = base[(row0 + i) * 64 + c];
    s += v;
    s2 = fmaf(v, v, s2);
  }
  __shared__ float rs[256], rs2[256];
  rs[t] = s; rs2[t] = s2;
  __syncthreads();
  if (t < 64) {
    s = rs[t] + rs[t + 64] + rs[t + 128] + rs[t + 192];
    s2 = rs2[t] + rs2[t + 64] + rs2[t + 128] + rs2[t + 192];
    atomicAdd(&ws[WS_SUM_OFF + plane * 64 + c], s);
    atomicAdd(&ws[WS_SUMSQ_OFF + plane * 64 + c], s2);
  }
}

__global__ void finalize_kernel(const float* __restrict__ gamma,
                                const float* __restrict__ beta,
                                float* __restrict__ ws) {
  int i = threadIdx.x;
  if (i < 192) {
    int c = i & 63;
    float mu = ws[WS_SUM_OFF + i] * (1.0f / 16384.0f);
    float var = ws[WS_SUMSQ_OFF + i] * (1.0f / 16384.0f) - mu * mu;
    var = fmaxf(var, 0.0f);
    float rstd = 1.0f / sqrtf(var + BN_EPS);
    float sc = gamma[c] * rstd;
    ws[WS_SCALE_OFF + i] = sc;
    ws[WS_SHIFT_OFF + i] = beta[c] - mu * sc;
  }
}

// ================= apply BN + relu + fused avgpool(3x3 s2 p1, count_include_pad) + pack fp16
// thread = (plane, px, 8-channel group); 393216 threads
__global__ __launch_bounds__(256) void apply_kernel(float* __restrict__ ws,
                                                    __half* __restrict__ planes) {
  int idx = blockIdx.x * 256 + threadIdx.x;  // < 393216
  int g = idx & 7;
  int p = (idx >> 3) & 16383;
  int pl = idx >> 17;
  int oy = p >> 7, ox = p & 127;
  int cb = g * 8;

  const float* conv = ws + WS_CONV_OFF;
  float4 a0 = *reinterpret_cast<const float4*>(conv + (size_t)idx * 8);
  float4 a1 = *reinterpret_cast<const float4*>(conv + (size_t)idx * 8 + 4);

  float sc[8], sh[8];
#pragma unroll
  for (int k = 0; k < 8; k++) {
    sc[k] = ws[WS_SCALE_OFF + pl * 64 + cb + k];
    sh[k] = ws[WS_SHIFT_OFF + pl * 64 + cb + k];
  }

  const ushort_t* inb = (const ushort_t*)(ws + WS_INBF_OFF) + pl * (256 * 256 * 64);
  float ps[8];
#pragma unroll
  for (int k = 0; k < 8; k++) ps[k] = 0.0f;
#pragma unroll
  for (int r = 0; r < 3; r++) {
    int yy = 2 * oy - 1 + r;
    if (yy < 0) continue;  // <= 255 always
#pragma unroll
    for (int s = 0; s < 3; s++) {
      int xx = 2 * ox - 1 + s;
      if (xx < 0) continue;
      union { int4 i4; ushort_t u[8]; } ub;
      ub.i4 = *reinterpret_cast<const int4*>(inb + (yy * 256 + xx) * 64 + cb);
#pragma unroll
      for (int k = 0; k < 8; k++) ps[k] += bf2f(ub.u[k]);
    }
  }

  float v[8] = {a0.x, a0.y, a0.z, a0.w, a1.x, a1.y, a1.z, a1.w};
  union { int4 i4; __half h[8]; } ob;
#pragma unroll
  for (int k = 0; k < 8; k++) {
    float r = fmaxf(fmaf(v[k], sc[k], sh[k]), 0.0f) + ps[k] * (1.0f / 9.0f);
    ob.h[k] = __float2half(r);
  }
  *reinterpret_cast<int4*>(planes + (size_t)idx * 8) = ob.i4;
}

// ================= bicubic sampling, 3 planes fused
__device__ __forceinline__ void cubic_w(float t, float w[4]) {
  float t1 = t + 1.0f;
  w[0] = ((A_COEF * t1 - 5.0f * A_COEF) * t1 + 8.0f * A_COEF) * t1 - 4.0f * A_COEF;
  w[1] = ((A_COEF + 2.0f) * t - (A_COEF + 3.0f)) * t * t + 1.0f;
  float s = 1.0f - t;
  w[2] = ((A_COEF + 2.0f) * s - (A_COEF + 3.0f)) * s * s + 1.0f;
  w[3] = 1.0f - w[0] - w[1] - w[2];
}

// 8 forced-in-flight global_load_dwordx4 (saddr + 32-bit voffset). Inline asm so
// the scheduler cannot sink the loads into the consume chain (compiler refused
// a 16-deep preload at HIP level in rounds 2 & 4 — VGPR stayed 32-52).
__device__ __forceinline__ void gl8(uintx4& q0, uintx4& q1, uintx4& q2, uintx4& q3,
                                    uintx4& q4, uintx4& q5, uintx4& q6, uintx4& q7,
                                    uint_t o0, uint_t o1, uint_t o2, uint_t o3,
                                    uint_t o4, uint_t o5, uint_t o6, uint_t o7,
                                    const __half* base) {
  asm volatile(
      "global_load_dwordx4 %0, %8, %16\n\t"
      "global_load_dwordx4 %1, %9, %16\n\t"
      "global_load_dwordx4 %2, %10, %16\n\t"
      "global_load_dwordx4 %3, %11, %16\n\t"
      "global_load_dwordx4 %4, %12, %16\n\t"
      "global_load_dwordx4 %5, %13, %16\n\t"
      "global_load_dwordx4 %6, %14, %16\n\t"
      "global_load_dwordx4 %7, %15, %16"
      : "=&v"(q0), "=&v"(q1), "=&v"(q2), "=&v"(q3),
        "=&v"(q4), "=&v"(q5), "=&v"(q6), "=&v"(q7)
      : "v"(o0), "v"(o1), "v"(o2), "v"(o3),
        "v"(o4), "v"(o5), "v"(o6), "v"(o7),
        "s"(base));
}

// One tap = one asm block: 8x v_fma_mix_f32 (fpext(f16)*w + acc, exact fma-f32
// numerics). Accumulators stay pinned across all 48 taps.
__device__ __forceinline__ void fma_mix_tap(float& a0, float& a1, float& a2, float& a3,
                                            float& a4, float& a5, float& a6, float& a7,
                                            uint_t qx, uint_t qy, uint_t qz, uint_t qw,
                                            float w) {
  asm("v_fma_mix_f32 %0, %8, %12, %0 op_sel:[0,0,0] op_sel_hi:[1,0,0]\n\t"
      "v_fma_mix_f32 %1, %8, %12, %1 op_sel:[1,0,0] op_sel_hi:[1,0,0]\n\t"
      "v_fma_mix_f32 %2, %9, %12, %2 op_sel:[0,0,0] op_sel_hi:[1,0,0]\n\t"
      "v_fma_mix_f32 %3, %9, %12, %3 op_sel:[1,0,0] op_sel_hi:[1,0,0]\n\t"
      "v_fma_mix_f32 %4, %10, %12, %4 op_sel:[0,0,0] op_sel_hi:[1,0,0]\n\t"
      "v_fma_mix_f32 %5, %10, %12, %5 op_sel:[1,0,0] op_sel_hi:[1,0,0]\n\t"
      "v_fma_mix_f32 %6, %11, %12, %6 op_sel:[0,0,0] op_sel_hi:[1,0,0]\n\t"
      "v_fma_mix_f32 %7, %11, %12, %7 op_sel:[1,0,0] op_sel_hi:[1,0,0]"
      : "+v"(a0), "+v"(a1), "+v"(a2), "+v"(a3),
        "+v"(a4), "+v"(a5), "+v"(a6), "+v"(a7)
      : "v"(qx), "v"(qy), "v"(qz), "v"(qw), "v"(w));
}

// group of 8 lanes = one point; lane l handles channels [l*8, l*8+8).
// v6: asm-forced 16-deep tap preload per plane + counted vmcnt(8)/vmcnt(0)
//     waits (consume oldest 8 while last 8 in flight). All compiler-level
//     loads (coords/noise) hoisted & consumed before any asm so compiler
//     auto-waitcnts can't interfere with the counted waits.
__global__ __launch_bounds__(256) void sample_kernel(const float* __restrict__ coords,
                                                     const float* __restrict__ noise,
                                                     const __half* __restrict__ planes,
                                                     float* __restrict__ out) {
  const int t = threadIdx.x;
  const int wv = t >> 6, lane = t & 63;
  const int g = lane >> 3, l = lane & 7;
  const int n = blockIdx.x * 32 + wv * 8 + g;

  const float c0 = (coords[n * 3 + 0] + 1.0f) * 0.5f;
  const float c1 = (coords[n * 3 + 1] + 1.0f) * 0.5f;
  const float c2 = (coords[n * 3 + 2] + 1.0f) * 0.5f;

  // precompute all 3 planes' sample geometry up front (consumes all noise loads)
  float wxA[3][4], wyA[3][4];
  int ixA[3], iyA[3];
#pragma unroll
  for (int p = 0; p < 3; p++) {
    float u = (p == 1) ? c1 : c0;   // p0:(c0,c1) p1:(c1,c2) p2:(c0,c2)
    float v = (p == 0) ? c1 : c2;
    u += noise[(p * N_POINTS + n) * 2 + 0];
    v += noise[(p * N_POINTS + n) * 2 + 1];
    float gx = fminf(fmaxf(fmaf(u, 63.5f, 63.5f), 0.0f), 127.0f);
    float gy = fminf(fmaxf(fmaf(v, 63.5f, 63.5f), 0.0f), 127.0f);
    float x0f = floorf(gx), y0f = floorf(gy);
    cubic_w(gx - x0f, wxA[p]);
    cubic_w(gy - y0f, wyA[p]);
    ixA[p] = (int)x0f;
    iyA[p] = (int)y0f;
  }

  float a0 = 0.f, a1 = 0.f, a2 = 0.f, a3 = 0.f;
  float a4 = 0.f, a5 = 0.f, a6 = 0.f, a7 = 0.f;

#pragma unroll
  for (int p = 0; p < 3; p++) {
    const int ix = ixA[p], iy = iyA[p];
    const int rb = p * (128 * 128 * 64) + l * 8;
    int ro[4], xo[4];
#pragma unroll
    for (int i = 0; i < 4; i++) ro[i] = rb + min(max(iy - 1 + i, 0), 127) * (128 * 64);
#pragma unroll
    for (int j = 0; j < 4; j++) xo[j] = min(max(ix - 1 + j, 0), 127) * 64;

    uint_t off[16];
#pragma unroll
    for (int i = 0; i < 4; i++)
#pragma unroll
      for (int j = 0; j < 4; j++) off[i * 4 + j] = (uint_t)(ro[i] + xo[j]) * 2u;

    uintx4 q0, q1, q2, q3, q4, q5, q6, q7, q8, q9, qa, qb, qc, qd, qe, qf;
    gl8(q0, q1, q2, q3, q4, q5, q6, q7,
        off[0], off[1], off[2], off[3], off[4], off[5], off[6], off[7], planes);
    gl8(q8, q9, qa, qb, qc, qd, qe, qf,
        off[8], off[9], off[10], off[11], off[12], off[13], off[14], off[15], planes);

    // oldest 8 done, newest 8 still in flight
    asm volatile("s_waitcnt vmcnt(8)");
    __builtin_amdgcn_sched_barrier(0);
    fma_mix_tap(a0,a1,a2,a3,a4,a5,a6,a7, q0.x,q0.y,q0.z,q0.w, wyA[p][0]*wxA[p][0]);
    fma_mix_tap(a0,a1,a2,a3,a4,a5,a6,a7, q1.x,q1.y,q1.z,q1.w, wyA[p][0]*wxA[p][1]);
    fma_mix_tap(a0,a1,a2,a3,a4,a5,a6,a7, q2.x,q2.y,q2.z,q2.w, wyA[p][0]*wxA[p][2]);
    fma_mix_tap(a0,a1,a2,a3,a4,a5,a6,a7, q3.x,q3.y,q3.z,q3.w, wyA[p][0]*wxA[p][3]);
    fma_mix_tap(a0,a1,a2,a3,a4,a5,a6,a7, q4.x,q4.y,q4.z,q4.w, wyA[p][1]*wxA[p][0]);
    fma_mix_tap(a0,a1,a2,a3,a4,a5,a6,a7, q5.x,q5.y,q5.z,q5.w, wyA[p][1]*wxA[p][1]);
    fma_mix_tap(a0,a1,a2,a3,a4,a5,a6,a7, q6.x,q6.y,q6.z,q6.w, wyA[p][1]*wxA[p][2]);
    fma_mix_tap(a0,a1,a2,a3,a4,a5,a6,a7, q7.x,q7.y,q7.z,q7.w, wyA[p][1]*wxA[p][3]);

    asm volatile("s_waitcnt vmcnt(0)");
    __builtin_amdgcn_sched_barrier(0);
    fma_mix_tap(a0,a1,a2,a3,a4,a5,a6,a7, q8.x,q8.y,q8.z,q8.w, wyA[p][2]*wxA[p][0]);
    fma_mix_tap(a0,a1,a2,a3,a4,a5,a6,a7, q9.x,q9.y,q9.z,q9.w, wyA[p][2]*wxA[p][1]);
    fma_mix_tap(a0,a1,a2,a3,a4,a5,a6,a7, qa.x,qa.y,qa.z,qa.w, wyA[p][2]*wxA[p][2]);
    fma_mix_tap(a0,a1,a2,a3,a4,a5,a6,a7, qb.x,qb.y,qb.z,qb.w, wyA[p][2]*wxA[p][3]);
    fma_mix_tap(a0,a1,a2,a3,a4,a5,a6,a7, qc.x,qc.y,qc.z,qc.w, wyA[p][3]*wxA[p][0]);
    fma_mix_tap(a0,a1,a2,a3,a4,a5,a6,a7, qd.x,qd.y,qd.z,qd.w, wyA[p][3]*wxA[p][1]);
    fma_mix_tap(a0,a1,a2,a3,a4,a5,a6,a7, qe.x,qe.y,qe.z,qe.w, wyA[p][3]*wxA[p][2]);
    fma_mix_tap(a0,a1,a2,a3,a4,a5,a6,a7, qf.x,qf.y,qf.z,qf.w, wyA[p][3]*wxA[p][3]);
  }

  float* op = out + (size_t)n * 64 + l * 8;
  *reinterpret_cast<float4*>(op)     = make_float4(a0, a1, a2, a3);
  *reinterpret_cast<float4*>(op + 4) = make_float4(a4, a5, a6, a7);
}

extern "C" void kernel_launch(void* const* d_in, const int* in_sizes, int n_in,
                              void* d_out, int out_size, void* d_ws, size_t ws_size,
                              hipStream_t stream) {
  const float* coords = (const float*)d_in[0];
  const float* noise  = (const float*)d_in[1];
  const float* px     = (const float*)d_in[2];
  const float* py     = (const float*)d_in[3];
  const float* pz     = (const float*)d_in[4];
  const float* conv_w = (const float*)d_in[5];
  // conv_b (d_in[6]) unused: bias cancels exactly under batch-stat BN
  const float* gamma  = (const float*)d_in[7];
  const float* beta   = (const float*)d_in[8];
  float* out = (float*)d_out;
  float* ws = (float*)d_ws;
  __half* planes = (__half*)(ws + WS_PLANES_OFF);

  wprep_kernel<<<144, 256, 0, stream>>>(conv_w, ws);
  transpose_kernel<<<dim3(4, 256, 3), 256, 0, stream>>>(px, py, pz, ws);
  conv_mfma_kernel<<<dim3(2, 128, 3), 256, 0, stream>>>(ws, ws);
  stats_kernel<<<192, 256, 0, stream>>>(ws);
  finalize_kernel<<<1, 256, 0, stream>>>(gamma, beta, ws);
  apply_kernel<<<1536, 256, 0, stream>>>(ws, planes);
  sample_kernel<<<15625, 256, 0, stream>>>(coords, noise, planes, out);
}